// Round 3
// baseline (1410.689 us; speedup 1.0000x reference)
//
#include <hip/hip_runtime.h>
#include <hip/hip_bf16.h>

#define T_STEPS 64
#define B_DIM 2048
#define U_DIM 1024
#define KITERS 32   // K-steps of 32 over U=1024

typedef __attribute__((ext_vector_type(8))) _Float16 h8;
typedef __attribute__((ext_vector_type(4))) float f4;

#define WAIT_VM0 __builtin_amdgcn_s_waitcnt(0x0F70)   // vmcnt(0)

__device__ __forceinline__ void async_cp16(const _Float16* g, _Float16* l) {
    __builtin_amdgcn_global_load_lds((const __attribute__((address_space(1))) void*)g,
                                     (__attribute__((address_space(3))) void*)l,
                                     16, 0, 0);
}

// ---------------- init kernels ----------------

// R: [U][2U] f32 row-major -> Rt: [2U][U] f16 (B^T layout)
__global__ void transpose_R(const float* __restrict__ R, _Float16* __restrict__ Rt) {
    __shared__ float tile[32][33];
    int nb = blockIdx.x * 32;
    int kb = blockIdx.y * 32;
    int tx = threadIdx.x, ty = threadIdx.y;   // block (32,8)
    #pragma unroll
    for (int i = ty; i < 32; i += 8)
        tile[i][tx] = R[(size_t)(kb + i) * (2 * U_DIM) + nb + tx];
    __syncthreads();
    #pragma unroll
    for (int i = ty; i < 32; i += 8)
        Rt[(size_t)(nb + i) * U_DIM + kb + tx] = (_Float16)tile[tx][i];
}

__global__ void init_state(const float* __restrict__ c0, _Float16* __restrict__ h0,
                           float* __restrict__ y, unsigned* __restrict__ bar) {
    int i = blockIdx.x * 256 + threadIdx.x;
    h0[i] = (_Float16)c0[i];
    if (i < 3 * B_DIM) y[i] = 0.f;
    if (i < 256) bar[i] = 0u;
}

// A-fragment direct-to-register load, L1-bypass (sc0): coherent with the
// sibling CUs' write-through c stores at the XCD L2 (same scheme the verified
// R2 kernel used via global_load_lds aux=1). Manual vmcnt pacing.
#define ALOAD1(dst, addr, OFFSTR) \
    asm volatile("global_load_dwordx4 %0, %1, off offset:" OFFSTR " sc0" \
                 : "=&v"(dst) : "v"(addr) : "memory")

#define ALOADG(S, OFFSTR) do { \
    ALOAD1(afq[S][0], am[0], OFFSTR); \
    ALOAD1(afq[S][1], am[1], OFFSTR); \
    ALOAD1(afq[S][2], am[2], OFFSTR); \
    ALOAD1(afq[S][3], am[3], OFFSTR); } while (0)

#define MFMA16(S) do { \
    _Pragma("unroll") \
    for (int mt = 0; mt < 4; ++mt) { \
        accF[mt][0] = __builtin_amdgcn_mfma_f32_16x16x32_f16(afq[S][mt], bff0, accF[mt][0], 0, 0, 0); \
        accF[mt][1] = __builtin_amdgcn_mfma_f32_16x16x32_f16(afq[S][mt], bff1, accF[mt][1], 0, 0, 0); \
        accC[mt][0] = __builtin_amdgcn_mfma_f32_16x16x32_f16(afq[S][mt], bfc0, accC[mt][0], 0, 0, 0); \
        accC[mt][1] = __builtin_amdgcn_mfma_f32_16x16x32_f16(afq[S][mt], bfc1, accC[mt][1], 0, 0, 0); \
    } } while (0)

// steady-state: groups KT..KT+3 outstanding at the wait -> vmcnt(12)=0x0F7C
#define KSTEP(KT, S, PFOFF) do { \
    h8 bff0 = *(const h8*)&lB[0][0][KT][rdoff]; \
    h8 bff1 = *(const h8*)&lB[0][1][KT][rdoff]; \
    h8 bfc0 = *(const h8*)&lB[1][0][KT][rdoff]; \
    h8 bfc1 = *(const h8*)&lB[1][1][KT][rdoff]; \
    __builtin_amdgcn_s_waitcnt(0x0F7C); \
    __builtin_amdgcn_sched_barrier(0); \
    MFMA16(S); \
    ALOADG(S, PFOFF); } while (0)

#define KTAIL(KT, S, WENC) do { \
    h8 bff0 = *(const h8*)&lB[0][0][KT][rdoff]; \
    h8 bff1 = *(const h8*)&lB[0][1][KT][rdoff]; \
    h8 bfc0 = *(const h8*)&lB[1][0][KT][rdoff]; \
    h8 bfc1 = *(const h8*)&lB[1][1][KT][rdoff]; \
    __builtin_amdgcn_s_waitcnt(WENC); \
    __builtin_amdgcn_sched_barrier(0); \
    MFMA16(S); } while (0)

// ---------------- persistent fused kernel ----------------
// Grid 256 = 32 u-chunks x 8 b-chunks, 1 block/CU (149 KB LDS).
// B panel LDS-resident for all steps; A fragments stream L2->registers
// directly (no LDS round-trip). Per-chunk 32-block cumulative barrier.
__global__ __launch_bounds__(256, 1) void persist(
    _Float16* __restrict__ h0, _Float16* __restrict__ h1,
    const _Float16* __restrict__ Rt,
    const float* __restrict__ x1_0, const float* __restrict__ x2_0,
    const float* __restrict__ kern, const float* __restrict__ bias,
    const float* __restrict__ okern,
    float* y,                         // [3][B]  (agent-scope atomics only)
    const float* __restrict__ inputs, // [T][B]
    float* __restrict__ out,          // [T][B]
    unsigned* bar)                    // 8 groups x 32-uint padded lines
{
    // 128 KB persistent B: [gate][nt][kt][16 rows x 32 swizzled halfs]
    __shared__ __align__(16) _Float16 lB[2][2][KITERS][512];
    __shared__ __align__(16) _Float16 lC[256 * 40];   // 20 KB epilogue staging
    __shared__ float x1s[256];                        // 1 KB

    const int tid    = threadIdx.x;
    const int wid    = tid >> 6;
    const int lane   = tid & 63;
    const int lane15 = lane & 15;
    const int quad   = lane >> 4;
    const int bid    = blockIdx.x;
    const int b0     = (bid & 7) * 256;
    const int u0     = (bid >> 3) * 32;
    const bool ub0   = (bid >> 3) == 0;
    const int wrow   = wid * 64;
    const int srow   = lane >> 2;
    const int schnk  = (((lane & 3) ^ (srow & 3) ^ ((srow >> 2) & 3)) * 8);
    const int sw     = ((quad ^ (lane15 & 3) ^ ((lane15 >> 2) & 3)) * 8);
    const int rdoff  = lane15 * 32 + sw;
    const int myb    = b0 + tid;
    unsigned* ctr   = &bar[(bid & 7) * 32];
    unsigned* xmask = &bar[(bid & 7) * 32 + 8];

    // ---- issue persistent-B DMAs (128 x 1KB regions, 32 per wave) ----
    #pragma unroll
    for (int gate = 0; gate < 2; ++gate)
        #pragma unroll
        for (int nt = 0; nt < 2; ++nt)
            #pragma unroll
            for (int i = 0; i < 8; ++i) {
                const int kt = wid + i * 4;
                async_cp16(Rt + (size_t)(gate * U_DIM + u0 + nt * 16 + srow) * U_DIM + kt * 32 + schnk,
                           &lB[gate][nt][kt][0]);
            }

    // ---- XCD purity probe + first rendezvous (overlaps B DMA flight) ----
    int* flag = (int*)x1s;
    if (tid == 0) {
        const unsigned xcc = (unsigned)__builtin_amdgcn_s_getreg(63508) & 31u; // HW_REG_XCC_ID
        __hip_atomic_fetch_or(xmask, 1u << xcc, __ATOMIC_RELAXED, __HIP_MEMORY_SCOPE_AGENT);
        __hip_atomic_fetch_add(ctr, 1u, __ATOMIC_RELAXED, __HIP_MEMORY_SCOPE_AGENT);
        while (__hip_atomic_load(ctr, __ATOMIC_RELAXED, __HIP_MEMORY_SCOPE_AGENT) < 32u)
            __builtin_amdgcn_s_sleep(1);
        const unsigned m = __hip_atomic_load(xmask, __ATOMIC_RELAXED, __HIP_MEMORY_SCOPE_AGENT);
        *flag = (__popc(m) == 1) ? 1 : 0;
    }
    __syncthreads();
    const bool xcd_pure = (*flag != 0);

    // ---- loop-invariant epilogue constants ----
    float kf[2], kc[2], bf_[2], bc_[2], ok_[2];
    #pragma unroll
    for (int nt = 0; nt < 2; ++nt) {
        const int u = u0 + nt * 16 + lane15;
        kf[nt]  = kern[u];        kc[nt]  = kern[U_DIM + u];
        bf_[nt] = bias[u];        bc_[nt] = bias[U_DIM + u];
        ok_[nt] = okern[u];
    }

    // ---- h gate values: register-carried across ALL steps ----
    _Float16 hv[4][2][4];
    #pragma unroll
    for (int mt = 0; mt < 4; ++mt)
        #pragma unroll
        for (int nt = 0; nt < 2; ++nt)
            #pragma unroll
            for (int reg = 0; reg < 4; ++reg)
                hv[mt][nt][reg] = h0[(size_t)(b0 + wrow + mt * 16 + quad * 4 + reg) * U_DIM
                                     + u0 + nt * 16 + lane15];

    float x1r = x1_0[myb];
    float x2r = x2_0[myb];

    WAIT_VM0;            // B panel + hv resident
    __syncthreads();     // all waves' B visible; flag consumed

    _Float16* hA_ = h0;
    _Float16* hB_ = h1;

    #pragma unroll 1
    for (int t = 0; t < T_STEPS; ++t) {
        // ---- integrator update (y finalized by previous step's barrier) ----
        // Stray VMEM here only shifts the first vmcnt wait (in-order retire).
        if (t > 0) {
            const float ip = inputs[(size_t)(t - 1) * B_DIM + myb];
            const float yp = __hip_atomic_load(&y[((t + 2) % 3) * B_DIM + myb],
                                               __ATOMIC_RELAXED, __HIP_MEMORY_SCOPE_AGENT);
            x1r = x1r + x2r;
            x2r = x2r + ip * yp;
        }
        if (ub0) {
            if (t > 0) out[(size_t)(t - 1) * B_DIM + myb] = x1r;
            if (t == T_STEPS - 1)
                out[(size_t)(T_STEPS - 1) * B_DIM + myb] = x1r + x2r;  // x1_{T}
            else
                __hip_atomic_store(&y[((t + 1) % 3) * B_DIM + myb], 0.f,
                                   __ATOMIC_RELAXED, __HIP_MEMORY_SCOPE_AGENT);
        }
        if (t == T_STEPS - 1) break;   // step-63 GEMM output is never consumed

        x1s[tid] = x1r;
        __syncthreads();   // x1s visible for this step's epilogue

        // ---- A-fragment base addresses (per mt) ----
        unsigned long long am[4];
        {
            const _Float16* ab = hA_ + (size_t)(b0 + wrow + lane15) * U_DIM + quad * 8;
            #pragma unroll
            for (int mt = 0; mt < 4; ++mt)
                am[mt] = (unsigned long long)(ab + (size_t)mt * 16 * U_DIM);
        }

        f4 accF[4][2], accC[4][2];
        #pragma unroll
        for (int mt = 0; mt < 4; ++mt)
            #pragma unroll
            for (int nt = 0; nt < 2; ++nt) {
                accF[mt][nt] = (f4){0.f, 0.f, 0.f, 0.f};
                accC[mt][nt] = (f4){0.f, 0.f, 0.f, 0.f};
            }

        // ---- K-loop: 4-deep register prefetch of A, B from LDS ----
        h8 afq[4][4];
        ALOADG(0, "0"); ALOADG(1, "64"); ALOADG(2, "128"); ALOADG(3, "192");
        KSTEP(0, 0, "256");   KSTEP(1, 1, "320");   KSTEP(2, 2, "384");   KSTEP(3, 3, "448");
        KSTEP(4, 0, "512");   KSTEP(5, 1, "576");   KSTEP(6, 2, "640");   KSTEP(7, 3, "704");
        KSTEP(8, 0, "768");   KSTEP(9, 1, "832");   KSTEP(10, 2, "896");  KSTEP(11, 3, "960");
        KSTEP(12, 0, "1024"); KSTEP(13, 1, "1088"); KSTEP(14, 2, "1152"); KSTEP(15, 3, "1216");
        KSTEP(16, 0, "1280"); KSTEP(17, 1, "1344"); KSTEP(18, 2, "1408"); KSTEP(19, 3, "1472");
        KSTEP(20, 0, "1536"); KSTEP(21, 1, "1600"); KSTEP(22, 2, "1664"); KSTEP(23, 3, "1728");
        KSTEP(24, 0, "1792"); KSTEP(25, 1, "1856"); KSTEP(26, 2, "1920"); KSTEP(27, 3, "1984");
        KTAIL(28, 0, 0x0F7C); KTAIL(29, 1, 0x0F78); KTAIL(30, 2, 0x0F74); KTAIL(31, 3, 0x0F70);

        // ---- epilogue: gates, c -> lC + hv register carry, y partials ----
        float* ycur = y + (t % 3) * B_DIM;
        #pragma unroll
        for (int mt = 0; mt < 4; ++mt) {
            const int rlb = wrow + mt * 16 + quad * 4;
            float psum[4] = {0.f, 0.f, 0.f, 0.f};
            #pragma unroll
            for (int nt = 0; nt < 2; ++nt) {
                const int ul = nt * 16 + lane15;
                #pragma unroll
                for (int reg = 0; reg < 4; ++reg) {
                    const int rl = rlb + reg;
                    const float x1 = x1s[rl];
                    const float xf = accF[mt][nt][reg] + x1 * kf[nt] + bf_[nt];
                    const float xc = accC[mt][nt][reg] + x1 * kc[nt] + bc_[nt];
                    const float fg = 1.f / (1.f + __expf(-xf));
                    const float th = 1.f - 2.f / (1.f + __expf(2.f * xc));
                    const float cv = fg * (float)hv[mt][nt][reg] + (1.f - fg) * th;
                    hv[mt][nt][reg] = (_Float16)cv;       // gate value for step t+1
                    lC[rl * 40 + ul] = (_Float16)cv;
                    psum[reg] += cv * ok_[nt];
                }
            }
            #pragma unroll
            for (int reg = 0; reg < 4; ++reg) {
                float s = psum[reg];
                s += __shfl_xor(s, 1);
                s += __shfl_xor(s, 2);
                s += __shfl_xor(s, 4);
                s += __shfl_xor(s, 8);
                if (lane15 == 0) atomicAdd(&ycur[b0 + rlb + reg], s);
            }
        }

        // ---- coalesced c write-out ----
        __syncthreads();
        #pragma unroll
        for (int j = 0; j < 4; ++j) {
            const int idx = j * 256 + tid;       // 1024 uint4 = 256 rows x 4
            const int row = idx >> 2;
            const int col = idx & 3;
            *(uint4*)&hB_[(size_t)(b0 + row) * U_DIM + u0 + col * 8] =
                *(const uint4*)&lC[row * 40 + col * 8];
        }

        { _Float16* tmp = hA_; hA_ = hB_; hB_ = tmp; }

        // ---- per-chunk 32-block barrier (cumulative counter) ----
        if (!xcd_pure) __builtin_amdgcn_fence(__ATOMIC_RELEASE, "agent");
        __syncthreads();   // drains vmcnt(0): c stores at XCD L2
        if (tid == 0) {
            __hip_atomic_fetch_add(ctr, 1u, __ATOMIC_RELAXED, __HIP_MEMORY_SCOPE_AGENT);
            while (__hip_atomic_load(ctr, __ATOMIC_RELAXED, __HIP_MEMORY_SCOPE_AGENT)
                   < 32u * (unsigned)(t + 2))            // +32 startup rendezvous
                __builtin_amdgcn_s_sleep(1);
        }
        __syncthreads();
        if (!xcd_pure) __builtin_amdgcn_fence(__ATOMIC_ACQUIRE, "agent");
    }
}

// ---------------- host ----------------
extern "C" void kernel_launch(void* const* d_in, const int* in_sizes, int n_in,
                              void* d_out, int out_size, void* d_ws, size_t ws_size,
                              hipStream_t stream) {
    const float* inputs = (const float*)d_in[0];
    const float* x1_0   = (const float*)d_in[1];
    const float* x2_0   = (const float*)d_in[2];
    const float* c0     = (const float*)d_in[3];
    const float* kern   = (const float*)d_in[4];
    const float* rker   = (const float*)d_in[5];
    const float* bias   = (const float*)d_in[6];
    const float* okern  = (const float*)d_in[7];
    float* out = (float*)d_out;

    _Float16* Rt = (_Float16*)d_ws;                       // 4 MB
    _Float16* h0 = Rt + (size_t)2 * U_DIM * U_DIM;        // 4 MB
    _Float16* h1 = h0 + (size_t)B_DIM * U_DIM;            // 4 MB
    float* y = (float*)(h1 + (size_t)B_DIM * U_DIM);      // 3*B
    unsigned* bar = (unsigned*)(y + 3 * B_DIM);           // 256 uints

    transpose_R<<<dim3(64, 32), dim3(32, 8), 0, stream>>>(rker, Rt);
    init_state<<<dim3(B_DIM * U_DIM / 256), dim3(256), 0, stream>>>(c0, h0, y, bar);
    persist<<<dim3(256), dim3(256), 0, stream>>>(h0, h1, Rt, x1_0, x2_0,
                                                 kern, bias, okern, y, inputs, out, bar);
}